// Round 1
// baseline (837.004 us; speedup 1.0000x reference)
//
#include <hip/hip_runtime.h>
#include <stdint.h>

// KVCacheAttention: B=4, Sq=2048, Scache=6144, Skv=8192, D=1024, scale=1/8.
// Pipeline: f32->bf16 convert; NT bf16 MFMA GEMMs (m97-style 128x128xBK32,
// global_load_lds width16, 2 barriers/K-step); per-batch QK^T + one-pass
// softmax (unnormalized bf16 P + row sums); batched PV GEMM with 1/sum epilogue.

#define DM 1024
#define NB 4
#define SQN 2048
#define SCC 6144
#define SKV 8192

typedef unsigned short u16;
typedef __attribute__((ext_vector_type(8))) short short8;
typedef __attribute__((ext_vector_type(4))) float f32x4;

__device__ __forceinline__ u16 f2bf(float x) {
  unsigned u = __builtin_bit_cast(unsigned, x);
  u += 0x7fffu + ((u >> 16) & 1u);   // RNE; inputs are finite
  return (u16)(u >> 16);
}

__device__ __forceinline__ void gll16(const void* g, void* l) {
  __builtin_amdgcn_global_load_lds(
      (const __attribute__((address_space(1))) void*)g,
      (__attribute__((address_space(3))) void*)l, 16, 0, 0);
}

// ---------------- conversions ----------------
__global__ __launch_bounds__(256) void k_cvt(const float* __restrict__ in,
                                             u16* __restrict__ out, long n4) {
  long i = (long)blockIdx.x * 256 + threadIdx.x;
  long st = (long)gridDim.x * 256;
  for (; i < n4; i += st) {
    float4 v = ((const float4*)in)[i];
    ushort4 u;
    u.x = f2bf(v.x); u.y = f2bf(v.y); u.z = f2bf(v.z); u.w = f2bf(v.w);
    ((ushort4*)out)[i] = u;
  }
}

// cached_key [4][6144][1024] f32 -> K bf16 [4][8192][1024] rows 0..6143
__global__ __launch_bounds__(256) void k_cvt_ck(const float* __restrict__ in,
                                                u16* __restrict__ out) {
  const long n4 = (long)NB * SCC * DM / 4;
  long i = (long)blockIdx.x * 256 + threadIdx.x;
  long st = (long)gridDim.x * 256;
  for (; i < n4; i += st) {
    float4 v = ((const float4*)in)[i];
    ushort4 u;
    u.x = f2bf(v.x); u.y = f2bf(v.y); u.z = f2bf(v.z); u.w = f2bf(v.w);
    long e = i * 4;
    int b = (int)(e / ((long)SCC * DM));
    long rem = e - (long)b * SCC * DM;
    *(ushort4*)(out + (long)b * SKV * DM + rem) = u;
  }
}

// ---------------- V^T builder ----------------
// VT[b][d][kv] <- cached_value f32 (kv<6144) | Vtmp bf16 (kv>=6144)
__global__ __launch_bounds__(256) void k_build_vt(const float* __restrict__ cv,
                                                  const u16* __restrict__ vtmp,
                                                  u16* __restrict__ VT) {
  __shared__ u16 t[64][65];
  const int kv0 = blockIdx.x * 64;
  const int d0 = blockIdx.y * 64;
  const int b = blockIdx.z;
  const int c = threadIdx.x & 63;
  const int r4 = threadIdx.x >> 6;  // 0..3
#pragma unroll
  for (int p = 0; p < 16; ++p) {
    int kr = p * 4 + r4;
    int kv = kv0 + kr;
    int d = d0 + c;
    u16 u;
    if (kv < SCC)
      u = f2bf(cv[((long)b * SCC + kv) * DM + d]);
    else
      u = vtmp[((long)b * SQN + (kv - SCC)) * DM + d];
    t[kr][c] = u;
  }
  __syncthreads();
#pragma unroll
  for (int p = 0; p < 16; ++p) {
    int dr = p * 4 + r4;
    VT[((long)b * DM + d0 + dr) * SKV + kv0 + c] = t[c][dr];
  }
}

// ---------------- softmax (one pass, row in registers) ----------------
// reads S f32 [2048][8192]; writes unnormalized exp as bf16 P, row sums f32.
__global__ __launch_bounds__(256) void k_softmax(const float* __restrict__ S,
                                                 u16* __restrict__ P,
                                                 float* __restrict__ sums) {
  const int row = blockIdx.x;
  const float* x = S + (long)row * SKV;
  const int t = threadIdx.x;
  const int lane = t & 63, wv = t >> 6;
  float4 v[8];
  float m = -3.0e38f;
#pragma unroll
  for (int j = 0; j < 8; ++j) {
    v[j] = ((const float4*)x)[t + 256 * j];
    m = fmaxf(m, fmaxf(fmaxf(v[j].x, v[j].y), fmaxf(v[j].z, v[j].w)));
  }
#pragma unroll
  for (int off = 32; off; off >>= 1) m = fmaxf(m, __shfl_xor(m, off));
  __shared__ float red[4];
  if (lane == 0) red[wv] = m;
  __syncthreads();
  m = fmaxf(fmaxf(red[0], red[1]), fmaxf(red[2], red[3]));
  const float c = 0.18033688011112042f;  // log2(e)/8  (scale=1/sqrt(64))
  float s = 0.f;
  u16* prow = P + (long)row * SKV;
#pragma unroll
  for (int j = 0; j < 8; ++j) {
    float ex = exp2f((v[j].x - m) * c);
    float ey = exp2f((v[j].y - m) * c);
    float ez = exp2f((v[j].z - m) * c);
    float ew = exp2f((v[j].w - m) * c);
    s += (ex + ey) + (ez + ew);
    ushort4 u;
    u.x = f2bf(ex); u.y = f2bf(ey); u.z = f2bf(ez); u.w = f2bf(ew);
    ((ushort4*)prow)[t + 256 * j] = u;
  }
#pragma unroll
  for (int off = 32; off; off >>= 1) s += __shfl_xor(s, off);
  __syncthreads();
  if (lane == 0) red[wv] = s;
  __syncthreads();
  if (t == 0) sums[row] = (red[0] + red[1]) + (red[2] + red[3]);
}

// ---------------- NT GEMM: C[m,n] = sum_k A[m,k]*B[n,k] (+bias)(/rowsum) ----------------
// 128x128 tile, BK=32, 256 thr (2x2 waves of 64x64), mfma_f32_16x16x32_bf16.
// dst index = (row>>rpbShift)*bstride + (roff + (row&mask))*ldc + col
template <bool BF16OUT>
__global__ __launch_bounds__(256) void k_gemm_nt(
    const u16* __restrict__ A, long az, const u16* __restrict__ B, long bz,
    int M, int N, int K, void* __restrict__ C, long cz, int ldc,
    const float* __restrict__ bias, const float* __restrict__ rowdiv, long rdz,
    int rpbShift, long bstride, int roff) {
  const int tid = threadIdx.x;
  const int lane = tid & 63;
  const int wv = tid >> 6;
  const int wr = wv >> 1, wc = wv & 1;
  const int z = blockIdx.z;
  const u16* Ab = A + (long)z * az;
  const u16* Bb = B + (long)z * bz;
  const int bm = blockIdx.y * 128;
  const int bn = blockIdx.x * 128;

  __shared__ u16 As[128 * 32];
  __shared__ u16 Bs[128 * 32];

  const int srow = tid >> 2;          // 0..63
  const int scol = (tid & 3) * 8;
  const u16* ga0 = Ab + (long)(bm + srow) * K + scol;
  const u16* ga1 = ga0 + (long)64 * K;
  const u16* gb0 = Bb + (long)(bn + srow) * K + scol;
  const u16* gb1 = gb0 + (long)64 * K;
  u16* la0 = &As[tid * 8];
  u16* la1 = &As[(256 + tid) * 8];
  u16* lb0 = &Bs[tid * 8];
  u16* lb1 = &Bs[(256 + tid) * 8];

  int aoffs[4], boffs[4];
#pragma unroll
  for (int m = 0; m < 4; ++m) aoffs[m] = (wr * 64 + m * 16 + (lane & 15)) * 32 + (lane >> 4) * 8;
#pragma unroll
  for (int n = 0; n < 4; ++n) boffs[n] = (wc * 64 + n * 16 + (lane & 15)) * 32 + (lane >> 4) * 8;

  f32x4 acc[4][4];
#pragma unroll
  for (int m = 0; m < 4; ++m)
#pragma unroll
    for (int n = 0; n < 4; ++n)
#pragma unroll
      for (int j = 0; j < 4; ++j) acc[m][n][j] = 0.0f;

  for (int k0 = 0; k0 < K; k0 += 32) {
    gll16(ga0, la0);
    gll16(ga1, la1);
    gll16(gb0, lb0);
    gll16(gb1, lb1);
    ga0 += 32; ga1 += 32; gb0 += 32; gb1 += 32;
    __syncthreads();  // drains vmcnt: LDS tiles ready
    short8 aF[4], bF[4];
#pragma unroll
    for (int m = 0; m < 4; ++m) aF[m] = *(const short8*)&As[aoffs[m]];
#pragma unroll
    for (int n = 0; n < 4; ++n) bF[n] = *(const short8*)&Bs[boffs[n]];
#pragma unroll
    for (int m = 0; m < 4; ++m)
#pragma unroll
      for (int n = 0; n < 4; ++n)
        acc[m][n] = __builtin_amdgcn_mfma_f32_16x16x32_bf16(aF[m], bF[n], acc[m][n], 0, 0, 0);
    __syncthreads();  // protect LDS from next stage
  }

  const int crow0 = bm + wr * 64;
  const int ccol0 = bn + wc * 64 + (lane & 15);
  const int rsub = (lane >> 4) * 4;
  const int rmask = (1 << rpbShift) - 1;
  float* Cf = (float*)C + (long)z * cz;
  u16* Ch = (u16*)C + (long)z * cz;
#pragma unroll
  for (int n = 0; n < 4; ++n) {
    int col = ccol0 + n * 16;
    float bb = bias ? bias[col] : 0.0f;
#pragma unroll
    for (int m = 0; m < 4; ++m) {
#pragma unroll
      for (int j = 0; j < 4; ++j) {
        int row = crow0 + m * 16 + rsub + j;
        float vv = acc[m][n][j] + bb;
        if (rowdiv) vv = vv / rowdiv[(long)z * rdz + row];
        long idx = (long)(row >> rpbShift) * bstride + (long)(roff + (row & rmask)) * ldc + col;
        if (BF16OUT) Ch[idx] = f2bf(vv);
        else Cf[idx] = vv;
      }
    }
  }
}

// ---------------- launch ----------------
extern "C" void kernel_launch(void* const* d_in, const int* in_sizes, int n_in,
                              void* d_out, int out_size, void* d_ws, size_t ws_size,
                              hipStream_t stream) {
  const float* hidden = (const float*)d_in[0];
  const float* ck = (const float*)d_in[1];
  const float* cv = (const float*)d_in[2];
  const float* Wq = (const float*)d_in[3];
  const float* bq = (const float*)d_in[4];
  const float* Wk = (const float*)d_in[5];
  const float* bk = (const float*)d_in[6];
  const float* Wv = (const float*)d_in[7];
  const float* bv = (const float*)d_in[8];

  char* w = (char*)d_ws;
  auto alloc = [&](size_t bytes) {
    char* p = w;
    w += (bytes + 255) & ~(size_t)255;
    return p;
  };
  u16* Hb = (u16*)alloc((size_t)NB * SQN * DM * 2);        // 16.8 MB
  u16* Wqb = (u16*)alloc((size_t)DM * DM * 2);
  u16* Wkb = (u16*)alloc((size_t)DM * DM * 2);
  u16* Wvb = (u16*)alloc((size_t)DM * DM * 2);
  u16* Qb = (u16*)alloc((size_t)NB * SQN * DM * 2);        // 16.8 MB
  u16* Kb = (u16*)alloc((size_t)NB * SKV * DM * 2);        // 67 MB
  u16* VT = (u16*)alloc((size_t)NB * DM * SKV * 2);        // 67 MB
  u16* Vtmp = (u16*)alloc((size_t)NB * SQN * DM * 2);      // 16.8 MB
  float* Sb = (float*)alloc((size_t)SQN * SKV * 4);        // 67 MB (per-batch reuse)
  u16* P = (u16*)alloc((size_t)NB * SQN * SKV * 2);        // 134 MB
  float* sums = (float*)alloc((size_t)NB * SQN * 4);
  (void)ws_size; (void)in_sizes; (void)n_in; (void)out_size;

  // conversions
  k_cvt<<<2048, 256, 0, stream>>>(hidden, Hb, (long)NB * SQN * DM / 4);
  k_cvt<<<512, 256, 0, stream>>>(Wq, Wqb, (long)DM * DM / 4);
  k_cvt<<<512, 256, 0, stream>>>(Wk, Wkb, (long)DM * DM / 4);
  k_cvt<<<512, 256, 0, stream>>>(Wv, Wvb, (long)DM * DM / 4);
  k_cvt_ck<<<4096, 256, 0, stream>>>(ck, Kb);

  // projections: M=8192, N=1024, K=1024
  dim3 gp(DM / 128, (NB * SQN) / 128, 1);
  k_gemm_nt<true><<<gp, 256, 0, stream>>>(Hb, 0, Wqb, 0, NB * SQN, DM, DM,
      Qb, 0, DM, bq, nullptr, 0, 11, (long)SQN * DM, 0);
  k_gemm_nt<true><<<gp, 256, 0, stream>>>(Hb, 0, Wkb, 0, NB * SQN, DM, DM,
      Kb, 0, DM, bk, nullptr, 0, 11, (long)SKV * DM, SCC);
  k_gemm_nt<true><<<gp, 256, 0, stream>>>(Hb, 0, Wvb, 0, NB * SQN, DM, DM,
      Vtmp, 0, DM, bv, nullptr, 0, 11, (long)SQN * DM, 0);

  // V^T
  k_build_vt<<<dim3(SKV / 64, DM / 64, NB), 256, 0, stream>>>(cv, Vtmp, VT);

  // attention: per-batch S GEMM + softmax
  for (int b = 0; b < NB; ++b) {
    dim3 gs(SKV / 128, SQN / 128, 1);
    k_gemm_nt<false><<<gs, 256, 0, stream>>>(
        Qb + (long)b * SQN * DM, 0, Kb + (long)b * SKV * DM, 0,
        SQN, SKV, DM, Sb, 0, SKV, nullptr, nullptr, 0, 11, 0, 0);
    k_softmax<<<SQN, 256, 0, stream>>>(Sb, P + (long)b * SQN * SKV, sums + b * SQN);
  }

  // PV batched over 4 batches: M=2048, N=1024, K=8192
  dim3 gv(DM / 128, SQN / 128, NB);
  k_gemm_nt<false><<<gv, 256, 0, stream>>>(
      P, (long)SQN * SKV, VT, (long)DM * SKV,
      SQN, DM, SKV, d_out, (long)SQN * DM, DM, nullptr, sums, SQN, 11, 0, 0);
}

// Round 2
// 615.512 us; speedup vs baseline: 1.3598x; 1.3598x over previous
//
#include <hip/hip_runtime.h>
#include <stdint.h>

// KVCacheAttention: B=4, Sq=2048, Scache=6144, Skv=8192, D=1024, scale=1/8.
// Round 2: fused QKV projection GEMM (N=3072, routing epilogue);
// batched S=QK^T GEMM with fused exp (no max-subtract; logits bounded) writing
// unnormalized bf16 P + atomic row sums; split-K(4) PV GEMM -> f32 partials;
// reduce+normalize kernel. All GEMMs: m97-style 128x128xBK32 mfma 16x16x32 bf16.

#define DM 1024
#define NB 4
#define SQN 2048
#define SCC 6144
#define SKV 8192
#define NSPLIT 4
#define KSP (SKV / NSPLIT)

typedef unsigned short u16;
typedef __attribute__((ext_vector_type(8))) short short8;
typedef __attribute__((ext_vector_type(4))) float f32x4;

__device__ __forceinline__ u16 f2bf(float x) {
  unsigned u = __builtin_bit_cast(unsigned, x);
  u += 0x7fffu + ((u >> 16) & 1u);  // RNE; inputs finite
  return (u16)(u >> 16);
}

__device__ __forceinline__ void gll16(const void* g, void* l) {
  __builtin_amdgcn_global_load_lds(
      (const __attribute__((address_space(1))) void*)g,
      (__attribute__((address_space(3))) void*)l, 16, 0, 0);
}

// ---------------- conversions ----------------
__global__ __launch_bounds__(256) void k_cvt(const float* __restrict__ in,
                                             u16* __restrict__ out, long n4) {
  long i = (long)blockIdx.x * 256 + threadIdx.x;
  long st = (long)gridDim.x * 256;
  for (; i < n4; i += st) {
    float4 v = ((const float4*)in)[i];
    ushort4 u;
    u.x = f2bf(v.x); u.y = f2bf(v.y); u.z = f2bf(v.z); u.w = f2bf(v.w);
    ((ushort4*)out)[i] = u;
  }
}

// cached_key [4][6144][1024] f32 -> K bf16 [4][8192][1024] rows 0..6143
__global__ __launch_bounds__(256) void k_cvt_ck(const float* __restrict__ in,
                                                u16* __restrict__ out) {
  const long n4 = (long)NB * SCC * DM / 4;
  long i = (long)blockIdx.x * 256 + threadIdx.x;
  long st = (long)gridDim.x * 256;
  for (; i < n4; i += st) {
    float4 v = ((const float4*)in)[i];
    ushort4 u;
    u.x = f2bf(v.x); u.y = f2bf(v.y); u.z = f2bf(v.z); u.w = f2bf(v.w);
    long e = i * 4;
    int b = (int)(e / ((long)SCC * DM));
    long rem = e - (long)b * SCC * DM;
    *(ushort4*)(out + (long)b * SKV * DM + rem) = u;
  }
}

// ---------------- V^T builder ----------------
__global__ __launch_bounds__(256) void k_build_vt(const float* __restrict__ cv,
                                                  const u16* __restrict__ vtmp,
                                                  u16* __restrict__ VT) {
  __shared__ u16 t[64][65];
  const int kv0 = blockIdx.x * 64;
  const int d0 = blockIdx.y * 64;
  const int b = blockIdx.z;
  const int c = threadIdx.x & 63;
  const int r4 = threadIdx.x >> 6;
#pragma unroll
  for (int p = 0; p < 16; ++p) {
    int kr = p * 4 + r4;
    int kv = kv0 + kr;
    int d = d0 + c;
    u16 u;
    if (kv < SCC)
      u = f2bf(cv[((long)b * SCC + kv) * DM + d]);
    else
      u = vtmp[((long)b * SQN + (kv - SCC)) * DM + d];
    t[kr][c] = u;
  }
  __syncthreads();
#pragma unroll
  for (int p = 0; p < 16; ++p) {
    int dr = p * 4 + r4;
    VT[((long)b * DM + d0 + dr) * SKV + kv0 + c] = t[c][dr];
  }
}

// ---------------- GEMM (NT, 128x128, BK=32) ----------------
// MODE 0: QKV projection. A=Hb[8192,1024], B0/1/2=Wq/Wk/Wv bf16 [1024,1024].
//         grid (24,64,1). Routing epilogue by col>>10 with bias.
// MODE 1: S=QK^T + exp. A=Qb, B0=Kb, z=batch. grid (64,16,4).
//         Writes unnormalized exp(S) bf16 to C0=P; atomicAdd row sums.
// MODE 2: PV split-K. A=P, B0=VT, z=(batch<<2)|split. grid (8,16,16).
//         Writes f32 partials to C0=Opart[z].
template <int MODE>
__global__ __launch_bounds__(256) void k_gemm(
    const u16* __restrict__ A, const u16* __restrict__ B0,
    const u16* __restrict__ B1, const u16* __restrict__ B2,
    void* __restrict__ C0, void* __restrict__ C1, void* __restrict__ C2,
    float* __restrict__ sums, const float* __restrict__ bias0,
    const float* __restrict__ bias1, const float* __restrict__ bias2) {
  const int tid = threadIdx.x;
  const int lane = tid & 63;
  const int wv = tid >> 6;
  const int wr = wv >> 1, wc = wv & 1;
  const int bm = blockIdx.y * 128;
  const int bn = blockIdx.x * 128;
  const int z = blockIdx.z;

  constexpr int LDA = (MODE == 2) ? SKV : DM;
  constexpr int KITERS = (MODE == 2) ? (KSP / 32) : (DM / 32);

  const u16* Ab;
  const u16* Bb;
  if constexpr (MODE == 0) {
    Ab = A + (long)bm * LDA;
    const int which = bn >> 10;
    const u16* Bsel = which == 0 ? B0 : (which == 1 ? B1 : B2);
    Bb = Bsel + (long)(bn & 1023) * LDA;
  } else if constexpr (MODE == 1) {
    Ab = A + ((long)z * SQN + bm) * LDA;
    Bb = B0 + ((long)z * SKV + bn) * LDA;
  } else {
    const int b = z >> 2, sp = z & 3;
    Ab = A + ((long)b * SQN + bm) * (long)SKV + sp * KSP;
    Bb = B0 + ((long)b * DM + bn) * (long)SKV + sp * KSP;
  }

  __shared__ u16 As[128 * 32];
  __shared__ u16 Bs[128 * 32];

  const int srow = tid >> 2;
  const int scol = (tid & 3) * 8;
  const u16* ga0 = Ab + (long)srow * LDA + scol;
  const u16* ga1 = ga0 + (long)64 * LDA;
  const u16* gb0 = Bb + (long)srow * LDA + scol;
  const u16* gb1 = gb0 + (long)64 * LDA;
  u16* la0 = &As[tid * 8];
  u16* la1 = &As[(256 + tid) * 8];
  u16* lb0 = &Bs[tid * 8];
  u16* lb1 = &Bs[(256 + tid) * 8];

  int aoffs[4], boffs[4];
#pragma unroll
  for (int m = 0; m < 4; ++m) aoffs[m] = (wr * 64 + m * 16 + (lane & 15)) * 32 + (lane >> 4) * 8;
#pragma unroll
  for (int n = 0; n < 4; ++n) boffs[n] = (wc * 64 + n * 16 + (lane & 15)) * 32 + (lane >> 4) * 8;

  f32x4 acc[4][4];
#pragma unroll
  for (int m = 0; m < 4; ++m)
#pragma unroll
    for (int n = 0; n < 4; ++n)
#pragma unroll
      for (int j = 0; j < 4; ++j) acc[m][n][j] = 0.0f;

  for (int k0 = 0; k0 < KITERS; ++k0) {
    gll16(ga0, la0);
    gll16(ga1, la1);
    gll16(gb0, lb0);
    gll16(gb1, lb1);
    ga0 += 32; ga1 += 32; gb0 += 32; gb1 += 32;
    __syncthreads();
    short8 aF[4], bF[4];
#pragma unroll
    for (int m = 0; m < 4; ++m) aF[m] = *(const short8*)&As[aoffs[m]];
#pragma unroll
    for (int n = 0; n < 4; ++n) bF[n] = *(const short8*)&Bs[boffs[n]];
#pragma unroll
    for (int m = 0; m < 4; ++m)
#pragma unroll
      for (int n = 0; n < 4; ++n)
        acc[m][n] = __builtin_amdgcn_mfma_f32_16x16x32_bf16(aF[m], bF[n], acc[m][n], 0, 0, 0);
    __syncthreads();
  }

  const int rsub = (lane >> 4) * 4;
  const int crow0 = bm + wr * 64 + rsub;
  const int ccol0 = bn + wc * 64 + (lane & 15);

  if constexpr (MODE == 0) {
    const int which = bn >> 10;
    const float* bp = which == 0 ? bias0 : (which == 1 ? bias1 : bias2);
    u16* Cq = (u16*)C0;
    u16* Ck = (u16*)C1;
    u16* Cv = (u16*)C2;
#pragma unroll
    for (int n = 0; n < 4; ++n) {
      int col = ccol0 + n * 16;
      int cc = col & 1023;
      float bb = bp[cc];
#pragma unroll
      for (int m = 0; m < 4; ++m)
#pragma unroll
        for (int j = 0; j < 4; ++j) {
          int row = crow0 + m * 16 + j;
          u16 hv = f2bf(acc[m][n][j] + bb);
          if (which == 1) {
            int b = row >> 11, s = row & 2047;
            Ck[((long)b * SKV + SCC + s) * DM + cc] = hv;
          } else if (which == 0) {
            Cq[(long)row * DM + cc] = hv;
          } else {
            Cv[(long)row * DM + cc] = hv;
          }
        }
    }
  } else if constexpr (MODE == 1) {
    u16* Pp = (u16*)C0 + (long)z * SQN * SKV;
    float* sb = sums + z * SQN;
    const float CE = 0.18033688011112042f;  // log2(e)/8
#pragma unroll
    for (int m = 0; m < 4; ++m)
#pragma unroll
      for (int j = 0; j < 4; ++j) {
        int row = crow0 + m * 16 + j;
        float part = 0.f;
#pragma unroll
        for (int n = 0; n < 4; ++n) {
          float e = exp2f(acc[m][n][j] * CE);
          part += e;
          Pp[(long)row * SKV + ccol0 + n * 16] = f2bf(e);
        }
        part += __shfl_xor(part, 1);
        part += __shfl_xor(part, 2);
        part += __shfl_xor(part, 4);
        part += __shfl_xor(part, 8);
        if ((lane & 15) == 0) atomicAdd(&sb[row], part);
      }
  } else {
    float* Cp = (float*)C0 + (long)z * SQN * DM;
#pragma unroll
    for (int n = 0; n < 4; ++n) {
      int col = ccol0 + n * 16;
#pragma unroll
      for (int m = 0; m < 4; ++m)
#pragma unroll
        for (int j = 0; j < 4; ++j) {
          int row = crow0 + m * 16 + j;
          Cp[(long)row * DM + col] = acc[m][n][j];
        }
    }
  }
}

// ---------------- reduce split-K partials + normalize ----------------
__global__ __launch_bounds__(256) void k_reduce(const float* __restrict__ Op,
                                                const float* __restrict__ sums,
                                                float* __restrict__ out) {
  const long n4 = (long)NB * SQN * DM / 4;
  long i = (long)blockIdx.x * 256 + threadIdx.x;
  if (i >= n4) return;
  long e = i * 4;
  int b = (int)(e / ((long)SQN * DM));
  long rem = e - (long)b * SQN * DM;
  int row = (int)(rem / DM);
  const long z4 = (long)SQN * DM / 4;
  long i0 = (long)(b * NSPLIT) * z4 + (rem >> 2);
  float4 a0 = ((const float4*)Op)[i0];
  float4 a1 = ((const float4*)Op)[i0 + z4];
  float4 a2 = ((const float4*)Op)[i0 + 2 * z4];
  float4 a3 = ((const float4*)Op)[i0 + 3 * z4];
  float inv = 1.0f / sums[b * SQN + row];
  float4 r;
  r.x = ((a0.x + a1.x) + (a2.x + a3.x)) * inv;
  r.y = ((a0.y + a1.y) + (a2.y + a3.y)) * inv;
  r.z = ((a0.z + a1.z) + (a2.z + a3.z)) * inv;
  r.w = ((a0.w + a1.w) + (a2.w + a3.w)) * inv;
  ((float4*)out)[i] = r;
}

// ---------------- launch ----------------
extern "C" void kernel_launch(void* const* d_in, const int* in_sizes, int n_in,
                              void* d_out, int out_size, void* d_ws, size_t ws_size,
                              hipStream_t stream) {
  const float* hidden = (const float*)d_in[0];
  const float* ck = (const float*)d_in[1];
  const float* cv = (const float*)d_in[2];
  const float* Wq = (const float*)d_in[3];
  const float* bq = (const float*)d_in[4];
  const float* Wk = (const float*)d_in[5];
  const float* bk = (const float*)d_in[6];
  const float* Wv = (const float*)d_in[7];
  const float* bv = (const float*)d_in[8];
  (void)in_sizes; (void)n_in; (void)out_size; (void)ws_size;

  char* base = (char*)d_ws;
  size_t off = 0;
  auto alloc = [&](size_t bytes) {
    char* p = base + off;
    off = (off + bytes + 255) & ~(size_t)255;
    return p;
  };
  // region0: dead before PV GEMM runs; Opart aliases it.
  u16* Hb = (u16*)alloc((size_t)NB * SQN * DM * 2);
  u16* Wqb = (u16*)alloc((size_t)DM * DM * 2);
  u16* Wkb = (u16*)alloc((size_t)DM * DM * 2);
  u16* Wvb = (u16*)alloc((size_t)DM * DM * 2);
  u16* Qb = (u16*)alloc((size_t)NB * SQN * DM * 2);
  u16* Kb = (u16*)alloc((size_t)NB * SKV * DM * 2);
  u16* Vtmp = (u16*)alloc((size_t)NB * SQN * DM * 2);
  float* Opart = (float*)base;  // [16][2048][1024] f32, aliases region0
  size_t opart_bytes = (size_t)NB * NSPLIT * SQN * DM * 4;
  if (off < opart_bytes) off = (opart_bytes + 255) & ~(size_t)255;
  u16* VT = (u16*)alloc((size_t)NB * DM * SKV * 2);
  u16* P = (u16*)alloc((size_t)NB * SQN * SKV * 2);
  float* sums = (float*)alloc((size_t)NB * SQN * 4);

  // conversions
  k_cvt<<<2048, 256, 0, stream>>>(hidden, Hb, (long)NB * SQN * DM / 4);
  k_cvt<<<512, 256, 0, stream>>>(Wq, Wqb, (long)DM * DM / 4);
  k_cvt<<<512, 256, 0, stream>>>(Wk, Wkb, (long)DM * DM / 4);
  k_cvt<<<512, 256, 0, stream>>>(Wv, Wvb, (long)DM * DM / 4);
  k_cvt_ck<<<4096, 256, 0, stream>>>(ck, Kb);

  // fused QKV projection: M=8192, N=3072, K=1024
  k_gemm<0><<<dim3(24, 64, 1), 256, 0, stream>>>(
      Hb, Wqb, Wkb, Wvb, Qb, Kb, Vtmp, nullptr, bq, bk, bv);

  // V^T
  k_build_vt<<<dim3(SKV / 64, DM / 64, NB), 256, 0, stream>>>(cv, Vtmp, VT);

  // S = QK^T with fused exp + row sums (batched over 4)
  hipMemsetAsync(sums, 0, (size_t)NB * SQN * 4, stream);
  k_gemm<1><<<dim3(SKV / 128, SQN / 128, NB), 256, 0, stream>>>(
      Qb, Kb, nullptr, nullptr, P, nullptr, nullptr, sums, nullptr, nullptr, nullptr);

  // PV split-K: z = (batch<<2)|split
  k_gemm<2><<<dim3(DM / 128, SQN / 128, NB * NSPLIT), 256, 0, stream>>>(
      P, VT, nullptr, nullptr, Opart, nullptr, nullptr, nullptr, nullptr, nullptr, nullptr);

  // reduce partials + normalize
  k_reduce<<<(NB * SQN * DM / 4 + 255) / 256, 256, 0, stream>>>(
      Opart, sums, (float*)d_out);
}

// Round 3
// 508.822 us; speedup vs baseline: 1.6450x; 1.2097x over previous
//
#include <hip/hip_runtime.h>
#include <stdint.h>

// KVCacheAttention: B=4, Sq=2048, Scache=6144, Skv=8192, D=1024, scale=1/8.
// Round 3: all GEMMs moved to a 256x256xBK64 8-wave 8-phase schedule
// (T2 LDS XOR-swizzle via pre-swizzled global source, T3/T4 counted vmcnt(2),
// T5 setprio, raw s_barrier -- no __syncthreads vmcnt(0) drain).
// MODE0: fused QKV projection (routing epilogue). MODE1: S=QK^T + exp +
// atomic row sums -> unnormalized bf16 P. MODE2: PV split-K(2) -> f32 partials.

#define DM 1024
#define NB 4
#define SQN 2048
#define SCC 6144
#define SKV 8192
#define NSPLIT 2
#define KSP (SKV / NSPLIT)

typedef unsigned short u16;
typedef __attribute__((ext_vector_type(8))) short short8;
typedef __attribute__((ext_vector_type(4))) float f32x4;

__device__ __forceinline__ u16 f2bf(float x) {
  unsigned u = __builtin_bit_cast(unsigned, x);
  u += 0x7fffu + ((u >> 16) & 1u);  // RNE; inputs finite
  return (u16)(u >> 16);
}

__device__ __forceinline__ void gll16(const void* g, void* l) {
  __builtin_amdgcn_global_load_lds(
      (const __attribute__((address_space(1))) void*)g,
      (__attribute__((address_space(3))) void*)l, 16, 0, 0);
}

#define FENCE() asm volatile("" ::: "memory")
#define BARRIER()                      \
  do {                                 \
    FENCE();                           \
    __builtin_amdgcn_s_barrier();      \
    FENCE();                           \
  } while (0)

// ---------------- conversions ----------------
__global__ __launch_bounds__(256) void k_cvt(const float* __restrict__ in,
                                             u16* __restrict__ out, long n4) {
  long i = (long)blockIdx.x * 256 + threadIdx.x;
  long st = (long)gridDim.x * 256;
  for (; i < n4; i += st) {
    float4 v = ((const float4*)in)[i];
    ushort4 u;
    u.x = f2bf(v.x); u.y = f2bf(v.y); u.z = f2bf(v.z); u.w = f2bf(v.w);
    ((ushort4*)out)[i] = u;
  }
}

// cached_key [4][6144][1024] f32 -> K bf16 [4][8192][1024] rows 0..6143
__global__ __launch_bounds__(256) void k_cvt_ck(const float* __restrict__ in,
                                                u16* __restrict__ out) {
  const long n4 = (long)NB * SCC * DM / 4;
  long i = (long)blockIdx.x * 256 + threadIdx.x;
  long st = (long)gridDim.x * 256;
  for (; i < n4; i += st) {
    float4 v = ((const float4*)in)[i];
    ushort4 u;
    u.x = f2bf(v.x); u.y = f2bf(v.y); u.z = f2bf(v.z); u.w = f2bf(v.w);
    long e = i * 4;
    int b = (int)(e / ((long)SCC * DM));
    long rem = e - (long)b * SCC * DM;
    *(ushort4*)(out + (long)b * SKV * DM + rem) = u;
  }
}

// ---------------- V^T builder ----------------
__global__ __launch_bounds__(256) void k_build_vt(const float* __restrict__ cv,
                                                  const u16* __restrict__ vtmp,
                                                  u16* __restrict__ VT) {
  __shared__ u16 t[64][65];
  const int kv0 = blockIdx.x * 64;
  const int d0 = blockIdx.y * 64;
  const int b = blockIdx.z;
  const int c = threadIdx.x & 63;
  const int r4 = threadIdx.x >> 6;
#pragma unroll
  for (int p = 0; p < 16; ++p) {
    int kr = p * 4 + r4;
    int kv = kv0 + kr;
    int d = d0 + c;
    u16 u;
    if (kv < SCC)
      u = f2bf(cv[((long)b * SCC + kv) * DM + d]);
    else
      u = vtmp[((long)b * SQN + (kv - SCC)) * DM + d];
    t[kr][c] = u;
  }
  __syncthreads();
#pragma unroll
  for (int p = 0; p < 16; ++p) {
    int dr = p * 4 + r4;
    VT[((long)b * DM + d0 + dr) * SKV + kv0 + c] = t[c][dr];
  }
}

// ---------------- 8-phase 256x256 NT GEMM ----------------
// 512 thr = 8 waves (2M x 4N); per-wave out 128x64; BK=64 (2 kk-slices);
// LDS 128 KiB: A[2][256][64] @0, B[2][256][64] @65536, XOR-swizzled
// (slot ^= row&7, slot = 16B unit) via pre-swizzled global source.
// Stage granularity: 8KB round (64 rows) = 1 gll16/thread; 8 rounds/K-tile.
// Phase p of K-tile kt stages 2 rounds of kt+1 into buf^1 (safe: buf^1 fully
// read last iteration, barriers passed). vmcnt(2) at phase 0 only.
template <int MODE>
__global__ __launch_bounds__(512, 2) void k_gemm8(
    const u16* __restrict__ A, const u16* __restrict__ B0,
    const u16* __restrict__ B1, const u16* __restrict__ B2,
    void* __restrict__ C0, void* __restrict__ C1, void* __restrict__ C2,
    float* __restrict__ sums, const float* __restrict__ bias0,
    const float* __restrict__ bias1, const float* __restrict__ bias2) {
  extern __shared__ char smem[];
  const int tid = threadIdx.x;
  const int lane = tid & 63;
  const int wv = tid >> 6;   // 0..7
  const int wr = wv >> 2;    // 0..1
  const int wc = wv & 3;     // 0..3
  const int bm = blockIdx.y * 256;
  const int bn = blockIdx.x * 256;
  const int z = blockIdx.z;

  constexpr int LD = (MODE == 2) ? SKV : DM;
  constexpr int NT = (MODE == 2) ? (KSP / 64) : (DM / 64);

  const u16 *Ab, *Bb;
  if constexpr (MODE == 0) {
    Ab = A + (long)bm * LD;
    const int which = bn >> 10;
    const u16* Bsel = which == 0 ? B0 : (which == 1 ? B1 : B2);
    Bb = Bsel + (long)(bn & 1023) * LD;
  } else if constexpr (MODE == 1) {
    Ab = A + ((long)z * SQN + bm) * LD;
    Bb = B0 + ((long)z * SKV + bn) * LD;
  } else {
    const int bb_ = z >> 1, sp = z & 1;
    Ab = A + ((long)bb_ * SQN + bm) * (long)SKV + sp * KSP;
    Bb = B0 + ((long)bb_ * DM + bn) * (long)SKV + sp * KSP;
  }

  // staging addresses: round r covers rows r*64..r*64+63; wave wv stages rows
  // wv*8+(lane>>3); global col pre-swizzled so linear LDS write = swizzled tile.
  const int srow = wv * 8 + (lane >> 3);
  const int scol = ((lane & 7) ^ (lane >> 3)) * 8;
  const u16* gA = Ab + (long)srow * LD + scol;
  const u16* gB = Bb + (long)srow * LD + scol;
  u16* lA = (u16*)smem + wv * 512 + lane * 8;            // + buf*16384 + r*4096
  u16* lB = (u16*)(smem + 65536) + wv * 512 + lane * 8;

  // prologue: stage K-tile 0 into buf0 (8 rounds)
#pragma unroll
  for (int r = 0; r < 4; ++r) gll16(gA + (long)r * 64 * LD, lA + r * 4096);
#pragma unroll
  for (int r = 0; r < 4; ++r) gll16(gB + (long)r * 64 * LD, lB + r * 4096);

  f32x4 acc[8][4];
#pragma unroll
  for (int m = 0; m < 8; ++m)
#pragma unroll
    for (int n = 0; n < 4; ++n)
#pragma unroll
      for (int j = 0; j < 4; ++j) acc[m][n][j] = 0.0f;

  const int arow = wr * 128 + (lane & 15);  // A tile row (row&7 == lane&7)
  const int brow = wc * 64 + (lane & 15);   // B tile row
  const int sw = lane & 7;                  // read-side swizzle
  const int s0 = lane >> 4;                 // base 16B slot

  short8 aF[8], bF[4];

  for (int kt = 0; kt < NT; ++kt) {
    const int b = kt & 1;
    const char* As = smem + b * 32768;
    const char* Bs = smem + 65536 + b * 32768;
    const int d = (b ^ 1) * 16384;  // dest elem offset for next tile
    const long knext = (kt + 1 < NT) ? (long)(kt + 1) * 64 : 0;
    const u16* gAn = gA + knext;
    const u16* gBn = gB + knext;

    // ---- phase 0: stage A r0,r1; vmcnt(2); bar; read kk0; MFMA n0,n1 ----
    gll16(gAn, lA + d);
    gll16(gAn + (long)64 * LD, lA + d + 4096);
    asm volatile("s_waitcnt vmcnt(2)" ::: "memory");
    BARRIER();
#pragma unroll
    for (int m = 0; m < 8; ++m)
      aF[m] = *(const short8*)(As + (arow + m * 16) * 128 + ((s0 ^ sw) * 16));
#pragma unroll
    for (int n = 0; n < 4; ++n)
      bF[n] = *(const short8*)(Bs + (brow + n * 16) * 128 + ((s0 ^ sw) * 16));
    __builtin_amdgcn_s_setprio(1);
#pragma unroll
    for (int m = 0; m < 8; ++m) {
      acc[m][0] = __builtin_amdgcn_mfma_f32_16x16x32_bf16(aF[m], bF[0], acc[m][0], 0, 0, 0);
      acc[m][1] = __builtin_amdgcn_mfma_f32_16x16x32_bf16(aF[m], bF[1], acc[m][1], 0, 0, 0);
    }
    __builtin_amdgcn_s_setprio(0);
    BARRIER();

    // ---- phase 1: stage A r2,r3; bar; MFMA n2,n3 (kk0) ----
    gll16(gAn + (long)128 * LD, lA + d + 2 * 4096);
    gll16(gAn + (long)192 * LD, lA + d + 3 * 4096);
    BARRIER();
    __builtin_amdgcn_s_setprio(1);
#pragma unroll
    for (int m = 0; m < 8; ++m) {
      acc[m][2] = __builtin_amdgcn_mfma_f32_16x16x32_bf16(aF[m], bF[2], acc[m][2], 0, 0, 0);
      acc[m][3] = __builtin_amdgcn_mfma_f32_16x16x32_bf16(aF[m], bF[3], acc[m][3], 0, 0, 0);
    }
    __builtin_amdgcn_s_setprio(0);
    BARRIER();

    // ---- phase 2: read kk1; stage B r0,r1; bar; MFMA n0,n1 (kk1) ----
#pragma unroll
    for (int m = 0; m < 8; ++m)
      aF[m] = *(const short8*)(As + (arow + m * 16) * 128 + (((s0 + 4) ^ sw) * 16));
#pragma unroll
    for (int n = 0; n < 4; ++n)
      bF[n] = *(const short8*)(Bs + (brow + n * 16) * 128 + (((s0 + 4) ^ sw) * 16));
    gll16(gBn, lB + d);
    gll16(gBn + (long)64 * LD, lB + d + 4096);
    BARRIER();
    __builtin_amdgcn_s_setprio(1);
#pragma unroll
    for (int m = 0; m < 8; ++m) {
      acc[m][0] = __builtin_amdgcn_mfma_f32_16x16x32_bf16(aF[m], bF[0], acc[m][0], 0, 0, 0);
      acc[m][1] = __builtin_amdgcn_mfma_f32_16x16x32_bf16(aF[m], bF[1], acc[m][1], 0, 0, 0);
    }
    __builtin_amdgcn_s_setprio(0);
    BARRIER();

    // ---- phase 3: stage B r2,r3; bar; MFMA n2,n3 (kk1) ----
    gll16(gBn + (long)128 * LD, lB + d + 2 * 4096);
    gll16(gBn + (long)192 * LD, lB + d + 3 * 4096);
    BARRIER();
    __builtin_amdgcn_s_setprio(1);
#pragma unroll
    for (int m = 0; m < 8; ++m) {
      acc[m][2] = __builtin_amdgcn_mfma_f32_16x16x32_bf16(aF[m], bF[2], acc[m][2], 0, 0, 0);
      acc[m][3] = __builtin_amdgcn_mfma_f32_16x16x32_bf16(aF[m], bF[3], acc[m][3], 0, 0, 0);
    }
    __builtin_amdgcn_s_setprio(0);
    BARRIER();
  }

  // ---------------- epilogue ----------------
  const int rsub = (lane >> 4) * 4;

  if constexpr (MODE == 0) {
    const int which = bn >> 10;
    const float* bp = which == 0 ? bias0 : (which == 1 ? bias1 : bias2);
    u16* Cq = (u16*)C0;
    u16* Ck = (u16*)C1;
    u16* Cv = (u16*)C2;
#pragma unroll
    for (int n = 0; n < 4; ++n) {
      int col = bn + wc * 64 + n * 16 + (lane & 15);
      int cc = col & 1023;
      float bb = bp[cc];
#pragma unroll
      for (int m = 0; m < 8; ++m)
#pragma unroll
        for (int j = 0; j < 4; ++j) {
          int row = bm + wr * 128 + m * 16 + rsub + j;
          u16 hv = f2bf(acc[m][n][j] + bb);
          if (which == 1) {
            int b = row >> 11, s = row & 2047;
            Ck[((long)b * SKV + SCC + s) * DM + cc] = hv;
          } else if (which == 0) {
            Cq[(long)row * DM + cc] = hv;
          } else {
            Cv[(long)row * DM + cc] = hv;
          }
        }
    }
  } else if constexpr (MODE == 1) {
    u16* Pp = (u16*)C0 + (long)z * SQN * SKV;
    float* sb = sums + z * SQN;
    const float CE = 0.18033688011112042f;  // log2(e)/8
#pragma unroll
    for (int m = 0; m < 8; ++m)
#pragma unroll
      for (int j = 0; j < 4; ++j) {
        int row = bm + wr * 128 + m * 16 + rsub + j;
        float part = 0.f;
#pragma unroll
        for (int n = 0; n < 4; ++n) {
          float e = exp2f(acc[m][n][j] * CE);
          part += e;
          Pp[(long)row * SKV + bn + wc * 64 + n * 16 + (lane & 15)] = f2bf(e);
        }
        part += __shfl_xor(part, 1);
        part += __shfl_xor(part, 2);
        part += __shfl_xor(part, 4);
        part += __shfl_xor(part, 8);
        if ((lane & 15) == 0) atomicAdd(&sb[row], part);
      }
  } else {
    float* Cp = (float*)C0 + (long)z * SQN * DM;
#pragma unroll
    for (int n = 0; n < 4; ++n) {
      int col = bn + wc * 64 + n * 16 + (lane & 15);
#pragma unroll
      for (int m = 0; m < 8; ++m)
#pragma unroll
        for (int j = 0; j < 4; ++j) {
          int row = bm + wr * 128 + m * 16 + rsub + j;
          Cp[(long)row * DM + col] = acc[m][n][j];
        }
    }
  }
}

// ---------------- reduce split-K partials + normalize ----------------
__global__ __launch_bounds__(256) void k_reduce(const float* __restrict__ Op,
                                                const float* __restrict__ sums,
                                                float* __restrict__ out) {
  const long n4 = (long)NB * SQN * DM / 4;
  long i = (long)blockIdx.x * 256 + threadIdx.x;
  if (i >= n4) return;
  long e = i * 4;
  int b = (int)(e / ((long)SQN * DM));
  long rem = e - (long)b * SQN * DM;
  int row = (int)(rem / DM);
  const long z4 = (long)SQN * DM / 4;
  long i0 = (long)(b * NSPLIT) * z4 + (rem >> 2);
  float4 a0 = ((const float4*)Op)[i0];
  float4 a1 = ((const float4*)Op)[i0 + z4];
  float inv = 1.0f / sums[b * SQN + row];
  float4 r;
  r.x = (a0.x + a1.x) * inv;
  r.y = (a0.y + a1.y) * inv;
  r.z = (a0.z + a1.z) * inv;
  r.w = (a0.w + a1.w) * inv;
  ((float4*)out)[i] = r;
}

// ---------------- launch ----------------
extern "C" void kernel_launch(void* const* d_in, const int* in_sizes, int n_in,
                              void* d_out, int out_size, void* d_ws, size_t ws_size,
                              hipStream_t stream) {
  const float* hidden = (const float*)d_in[0];
  const float* ck = (const float*)d_in[1];
  const float* cv = (const float*)d_in[2];
  const float* Wq = (const float*)d_in[3];
  const float* bq = (const float*)d_in[4];
  const float* Wk = (const float*)d_in[5];
  const float* bk = (const float*)d_in[6];
  const float* Wv = (const float*)d_in[7];
  const float* bv = (const float*)d_in[8];
  (void)in_sizes; (void)n_in; (void)out_size; (void)ws_size;

  hipFuncSetAttribute(reinterpret_cast<const void*>(&k_gemm8<0>),
                      hipFuncAttributeMaxDynamicSharedMemorySize, 131072);
  hipFuncSetAttribute(reinterpret_cast<const void*>(&k_gemm8<1>),
                      hipFuncAttributeMaxDynamicSharedMemorySize, 131072);
  hipFuncSetAttribute(reinterpret_cast<const void*>(&k_gemm8<2>),
                      hipFuncAttributeMaxDynamicSharedMemorySize, 131072);

  char* base = (char*)d_ws;
  size_t off = 0;
  auto alloc = [&](size_t bytes) {
    char* p = base + off;
    off = (off + bytes + 255) & ~(size_t)255;
    return p;
  };
  // region0 (dead before PV): Hb, weights, Qb, Kb, Vtmp. Opart aliases it.
  u16* Hb = (u16*)alloc((size_t)NB * SQN * DM * 2);
  u16* Wqb = (u16*)alloc((size_t)DM * DM * 2);
  u16* Wkb = (u16*)alloc((size_t)DM * DM * 2);
  u16* Wvb = (u16*)alloc((size_t)DM * DM * 2);
  u16* Qb = (u16*)alloc((size_t)NB * SQN * DM * 2);
  u16* Kb = (u16*)alloc((size_t)NB * SKV * DM * 2);
  u16* Vtmp = (u16*)alloc((size_t)NB * SQN * DM * 2);
  float* Opart = (float*)base;  // [NB*NSPLIT][2048][1024] f32, aliases region0
  size_t opart_bytes = (size_t)NB * NSPLIT * SQN * DM * 4;
  if (off < opart_bytes) off = (opart_bytes + 255) & ~(size_t)255;
  u16* VT = (u16*)alloc((size_t)NB * DM * SKV * 2);
  u16* P = (u16*)alloc((size_t)NB * SQN * SKV * 2);
  float* sums = (float*)alloc((size_t)NB * SQN * 4);

  // conversions
  k_cvt<<<2048, 256, 0, stream>>>(hidden, Hb, (long)NB * SQN * DM / 4);
  k_cvt<<<512, 256, 0, stream>>>(Wq, Wqb, (long)DM * DM / 4);
  k_cvt<<<512, 256, 0, stream>>>(Wk, Wkb, (long)DM * DM / 4);
  k_cvt<<<512, 256, 0, stream>>>(Wv, Wvb, (long)DM * DM / 4);
  k_cvt_ck<<<4096, 256, 0, stream>>>(ck, Kb);

  // fused QKV projection: M=8192, N=3072, K=1024
  k_gemm8<0><<<dim3(12, 32, 1), 512, 131072, stream>>>(
      Hb, Wqb, Wkb, Wvb, Qb, Kb, Vtmp, nullptr, bq, bk, bv);

  // V^T
  k_build_vt<<<dim3(SKV / 64, DM / 64, NB), 256, 0, stream>>>(cv, Vtmp, VT);

  // S = QK^T with fused exp + row sums (batched over 4)
  hipMemsetAsync(sums, 0, (size_t)NB * SQN * 4, stream);
  k_gemm8<1><<<dim3(SKV / 256, SQN / 256, NB), 512, 131072, stream>>>(
      Qb, Kb, nullptr, nullptr, P, nullptr, nullptr, sums, nullptr, nullptr, nullptr);

  // PV split-K(2): z = (batch<<1)|split
  k_gemm8<2><<<dim3(DM / 256, SQN / 256, NB * NSPLIT), 512, 131072, stream>>>(
      P, VT, nullptr, nullptr, Opart, nullptr, nullptr, nullptr, nullptr, nullptr, nullptr);

  // reduce partials + normalize
  k_reduce<<<(NB * SQN * DM / 4 + 255) / 256, 256, 0, stream>>>(
      Opart, sums, (float*)d_out);
}